// Round 1
// baseline (72.617 us; speedup 1.0000x reference)
//
#include <hip/hip_runtime.h>

// Exponential concordance loss:
// loss_sum = sum over (a,b) with dur[b] < dur[a] and ev[b]==1 of exp(p[a]-p[b])
//          = sum_a exp(p[a]) * sum_{b valid} exp(-p[b])
// out = loss_sum / num_pairs
//
// Separable per pair: accumulate epos[a]*w[b] over any partition of pair space.

#define TPB 256
#define ROWS_PER_PASS 32   // threads covering the 'a' axis per column b

__global__ void precompute_kernel(const float* __restrict__ preds,
                                  const float* __restrict__ targets,
                                  float* __restrict__ w,
                                  float* __restrict__ epos,
                                  float* __restrict__ dur,
                                  int n) {
    int i = blockIdx.x * blockDim.x + threadIdx.x;
    if (i < n) {
        float p  = preds[i];
        float d  = targets[2 * i];
        float ev = targets[2 * i + 1];
        epos[i] = expf(p);
        w[i]    = (ev == 1.0f) ? expf(-p) : 0.0f;
        dur[i]  = d;
    }
}

__global__ void __launch_bounds__(TPB) pair_kernel(const float* __restrict__ w,
                                                   const float* __restrict__ epos,
                                                   const float* __restrict__ dur,
                                                   float* __restrict__ psum,
                                                   int* __restrict__ pcnt,
                                                   int n) {
    int t  = blockIdx.x * blockDim.x + threadIdx.x;
    int b  = t % n;            // column index, fixed per thread (coalesced)
    int a0 = t / n;            // starting row; uniform within a block

    float dur_b = dur[b];
    float w_b   = w[b];

    float lsum = 0.0f;
    int   lcnt = 0;
    for (int a = a0; a < n; a += ROWS_PER_PASS) {
        float dur_a  = dur[a];     // block-uniform address -> broadcast
        float epos_a = epos[a];
        bool  valid  = dur_b < dur_a;
        lsum += valid ? epos_a : 0.0f;
        lcnt += valid ? 1 : 0;
    }
    // mask requires ev[b]==1  <=>  w_b > 0 (exp is always > 0)
    if (w_b > 0.0f) {
        lsum *= w_b;
    } else {
        lsum = 0.0f;
        lcnt = 0;
    }

    __shared__ float ssum[TPB];
    __shared__ int   scnt[TPB];
    ssum[threadIdx.x] = lsum;
    scnt[threadIdx.x] = lcnt;
    __syncthreads();
    for (int s = TPB / 2; s > 0; s >>= 1) {
        if (threadIdx.x < s) {
            ssum[threadIdx.x] += ssum[threadIdx.x + s];
            scnt[threadIdx.x] += scnt[threadIdx.x + s];
        }
        __syncthreads();
    }
    if (threadIdx.x == 0) {
        psum[blockIdx.x] = ssum[0];
        pcnt[blockIdx.x] = scnt[0];
    }
}

__global__ void __launch_bounds__(TPB) finalize_kernel(const float* __restrict__ psum,
                                                       const int* __restrict__ pcnt,
                                                       float* __restrict__ out,
                                                       int nb) {
    __shared__ double    ss[TPB];
    __shared__ long long sc[TPB];
    double    ls = 0.0;
    long long lc = 0;
    for (int i = threadIdx.x; i < nb; i += TPB) {
        ls += (double)psum[i];
        lc += (long long)pcnt[i];
    }
    ss[threadIdx.x] = ls;
    sc[threadIdx.x] = lc;
    __syncthreads();
    for (int s = TPB / 2; s > 0; s >>= 1) {
        if (threadIdx.x < s) {
            ss[threadIdx.x] += ss[threadIdx.x + s];
            sc[threadIdx.x] += sc[threadIdx.x + s];
        }
        __syncthreads();
    }
    if (threadIdx.x == 0) {
        out[0] = (sc[0] > 0) ? (float)(ss[0] / (double)sc[0]) : 0.0f;
    }
}

extern "C" void kernel_launch(void* const* d_in, const int* in_sizes, int n_in,
                              void* d_out, int out_size, void* d_ws, size_t ws_size,
                              hipStream_t stream) {
    const float* preds   = (const float*)d_in[0];
    const float* targets = (const float*)d_in[1];
    float* out = (float*)d_out;
    int n = in_sizes[0];   // 8192

    // ws layout: w[n], epos[n], dur[n], psum[nblocks], pcnt[nblocks]
    float* w    = (float*)d_ws;
    float* epos = w + n;
    float* dur  = epos + n;
    int total_threads = ROWS_PER_PASS * n;          // 32 * 8192 = 262144
    int nblocks = total_threads / TPB;              // 1024
    float* psum = dur + n;
    int*   pcnt = (int*)(psum + nblocks);

    int pre_blocks = (n + TPB - 1) / TPB;
    precompute_kernel<<<pre_blocks, TPB, 0, stream>>>(preds, targets, w, epos, dur, n);
    pair_kernel<<<nblocks, TPB, 0, stream>>>(w, epos, dur, psum, pcnt, n);
    finalize_kernel<<<1, TPB, 0, stream>>>(psum, pcnt, out, nblocks);
}

// Round 2
// 20.825 us; speedup vs baseline: 3.4869x; 3.4869x over previous
//
#include <hip/hip_runtime.h>

// Exponential concordance loss:
// loss_sum = sum over (a,b) with dur[b] < dur[a] and ev[b]==1 of exp(p[a]-p[b])
//          = sum_a epos[a] * sum_{b: dur_b<dur_a} w[b],  w[b]=ev[b]?exp(-p[b]):0
// out = loss_sum / num_pairs
//
// pair_kernel: each thread owns NB=4 columns b (regs), block stages ACHUNK
// rows a in LDS (uniform-address broadcast reads), unrolled FMA-ish loop.

#define TPB 256
#define NB 4          // columns per thread (register-resident)
#define ACHUNK 128    // rows staged in LDS per block

__global__ void precompute_kernel(const float* __restrict__ preds,
                                  const float* __restrict__ targets,
                                  float2* __restrict__ colb,   // (dur_b, w_b)
                                  float2* __restrict__ rowa,   // (dur_a, epos_a)
                                  int n) {
    int i = blockIdx.x * blockDim.x + threadIdx.x;
    if (i < n) {
        float p  = preds[i];
        float d  = targets[2 * i];
        float ev = targets[2 * i + 1];
        rowa[i] = make_float2(d, expf(p));
        colb[i] = make_float2(d, (ev == 1.0f) ? expf(-p) : 0.0f);
    }
}

__global__ void __launch_bounds__(TPB) pair_kernel(const float2* __restrict__ colb,
                                                   const float2* __restrict__ rowa,
                                                   float* __restrict__ psum,
                                                   int* __restrict__ pcnt,
                                                   int n) {
    const int colGroups = n / (TPB * NB);          // 8192/1024 = 8
    const int cg = blockIdx.x % colGroups;
    const int ac = blockIdx.x / colGroups;
    const int base_b = cg * TPB * NB + threadIdx.x;
    const int base_a = ac * ACHUNK;

    __shared__ float2 sa[ACHUNK];
    for (int i = threadIdx.x; i < ACHUNK; i += TPB)
        sa[i] = rowa[base_a + i];

    float db[NB], wb[NB];
#pragma unroll
    for (int k = 0; k < NB; ++k) {
        float2 c = colb[base_b + k * TPB];         // coalesced
        db[k] = c.x;
        wb[k] = c.y;
    }
    __syncthreads();

    float sum[NB];
    float cntf[NB];
#pragma unroll
    for (int k = 0; k < NB; ++k) { sum[k] = 0.0f; cntf[k] = 0.0f; }

#pragma unroll 8
    for (int i = 0; i < ACHUNK; ++i) {
        float2 a = sa[i];                          // uniform -> broadcast
#pragma unroll
        for (int k = 0; k < NB; ++k) {
            bool v = db[k] < a.x;
            sum[k]  += v ? a.y : 0.0f;
            cntf[k] += v ? 1.0f : 0.0f;            // <= ACHUNK, exact in fp32
        }
    }

    float lsum = 0.0f;
    int   lcnt = 0;
#pragma unroll
    for (int k = 0; k < NB; ++k) {
        if (wb[k] > 0.0f) {                        // ev[b]==1  <=>  w_b>0
            lsum += wb[k] * sum[k];
            lcnt += (int)cntf[k];
        }
    }

    __shared__ float ssum[TPB];
    __shared__ int   scnt[TPB];
    ssum[threadIdx.x] = lsum;
    scnt[threadIdx.x] = lcnt;
    __syncthreads();
    for (int s = TPB / 2; s > 0; s >>= 1) {
        if (threadIdx.x < s) {
            ssum[threadIdx.x] += ssum[threadIdx.x + s];
            scnt[threadIdx.x] += scnt[threadIdx.x + s];
        }
        __syncthreads();
    }
    if (threadIdx.x == 0) {
        psum[blockIdx.x] = ssum[0];
        pcnt[blockIdx.x] = scnt[0];
    }
}

__global__ void __launch_bounds__(TPB) finalize_kernel(const float* __restrict__ psum,
                                                       const int* __restrict__ pcnt,
                                                       float* __restrict__ out,
                                                       int nb) {
    __shared__ double    ss[TPB];
    __shared__ long long sc[TPB];
    double    ls = 0.0;
    long long lc = 0;
    for (int i = threadIdx.x; i < nb; i += TPB) {
        ls += (double)psum[i];
        lc += (long long)pcnt[i];
    }
    ss[threadIdx.x] = ls;
    sc[threadIdx.x] = lc;
    __syncthreads();
    for (int s = TPB / 2; s > 0; s >>= 1) {
        if (threadIdx.x < s) {
            ss[threadIdx.x] += ss[threadIdx.x + s];
            sc[threadIdx.x] += sc[threadIdx.x + s];
        }
        __syncthreads();
    }
    if (threadIdx.x == 0) {
        out[0] = (sc[0] > 0) ? (float)(ss[0] / (double)sc[0]) : 0.0f;
    }
}

extern "C" void kernel_launch(void* const* d_in, const int* in_sizes, int n_in,
                              void* d_out, int out_size, void* d_ws, size_t ws_size,
                              hipStream_t stream) {
    const float* preds   = (const float*)d_in[0];
    const float* targets = (const float*)d_in[1];
    float* out = (float*)d_out;
    int n = in_sizes[0];   // 8192

    // ws layout: colb[n] float2, rowa[n] float2, psum[nblocks], pcnt[nblocks]
    float2* colb = (float2*)d_ws;
    float2* rowa = colb + n;
    int colGroups = n / (TPB * NB);                // 8
    int aChunks   = n / ACHUNK;                    // 64
    int nblocks   = colGroups * aChunks;           // 512
    float* psum = (float*)(rowa + n);
    int*   pcnt = (int*)(psum + nblocks);

    int pre_blocks = (n + TPB - 1) / TPB;
    precompute_kernel<<<pre_blocks, TPB, 0, stream>>>(preds, targets, colb, rowa, n);
    pair_kernel<<<nblocks, TPB, 0, stream>>>(colb, rowa, psum, pcnt, n);
    finalize_kernel<<<1, TPB, 0, stream>>>(psum, pcnt, out, nblocks);
}

// Round 3
// 15.971 us; speedup vs baseline: 4.5468x; 1.3039x over previous
//
#include <hip/hip_runtime.h>

// Exponential concordance loss (single fused pair kernel + tiny finalize):
// loss_sum = sum over (a,b) with dur[b] < dur[a] and ev[b]==1 of exp(p[a]-p[b])
//          = sum_a epos[a] * sum_{b: dur_b<dur_a} w[b],  w[b]=ev[b]?exp(-p[b]):0
// out = loss_sum / num_pairs
//
// pair_fused: block = (colGroup cg of TPB*NB columns) x (aChunk of ACHUNK rows).
// Rows staged in LDS as float2(dur, exp(p)) computed in-kernel; columns held in
// registers as (dur_b, w_b) computed in-kernel. No separate precompute pass.

#define TPB 256
#define NB 8          // columns per thread (register-resident)
#define ACHUNK 64     // rows staged in LDS per block

__global__ void __launch_bounds__(TPB) pair_fused(const float* __restrict__ preds,
                                                  const float2* __restrict__ targets, // (dur, ev)
                                                  float* __restrict__ psum,
                                                  int* __restrict__ pcnt,
                                                  int n) {
    const int colGroups = n / (TPB * NB);          // 8192/2048 = 4
    const int cg = blockIdx.x % colGroups;
    const int ac = blockIdx.x / colGroups;
    const int base_a = ac * ACHUNK;
    const int base_b = cg * TPB * NB + threadIdx.x;

    __shared__ float2 sa[ACHUNK];                  // (dur_a, epos_a)
    if (threadIdx.x < ACHUNK) {
        int a = base_a + threadIdx.x;
        float2 t = targets[a];
        sa[threadIdx.x] = make_float2(t.x, __expf(preds[a]));
    }

    float db[NB], wb[NB];
#pragma unroll
    for (int k = 0; k < NB; ++k) {
        int b = base_b + k * TPB;                  // coalesced
        float2 t = targets[b];
        float  p = preds[b];
        db[k] = t.x;
        wb[k] = (t.y == 1.0f) ? __expf(-p) : 0.0f;
    }
    __syncthreads();

    float sum[NB];
    int   cnt[NB];
#pragma unroll
    for (int k = 0; k < NB; ++k) { sum[k] = 0.0f; cnt[k] = 0; }

#pragma unroll 8
    for (int i = 0; i < ACHUNK; ++i) {
        float2 a = sa[i];                          // uniform address -> broadcast
#pragma unroll
        for (int k = 0; k < NB; ++k) {
            bool v = db[k] < a.x;
            sum[k] += v ? a.y : 0.0f;
            cnt[k] += v;
        }
    }

    float lsum = 0.0f;
    int   lcnt = 0;
#pragma unroll
    for (int k = 0; k < NB; ++k) {
        if (wb[k] > 0.0f) {                        // ev[b]==1  <=>  w_b>0
            lsum += wb[k] * sum[k];
            lcnt += cnt[k];
        }
    }

    __shared__ float ssum[TPB];
    __shared__ int   scnt[TPB];
    ssum[threadIdx.x] = lsum;
    scnt[threadIdx.x] = lcnt;
    __syncthreads();
    for (int s = TPB / 2; s > 0; s >>= 1) {
        if (threadIdx.x < s) {
            ssum[threadIdx.x] += ssum[threadIdx.x + s];
            scnt[threadIdx.x] += scnt[threadIdx.x + s];
        }
        __syncthreads();
    }
    if (threadIdx.x == 0) {
        psum[blockIdx.x] = ssum[0];
        pcnt[blockIdx.x] = scnt[0];
    }
}

__global__ void __launch_bounds__(TPB) finalize_kernel(const float* __restrict__ psum,
                                                       const int* __restrict__ pcnt,
                                                       float* __restrict__ out,
                                                       int nb) {
    __shared__ double    ss[TPB];
    __shared__ long long sc[TPB];
    double    ls = 0.0;
    long long lc = 0;
    for (int i = threadIdx.x; i < nb; i += TPB) {
        ls += (double)psum[i];
        lc += (long long)pcnt[i];
    }
    ss[threadIdx.x] = ls;
    sc[threadIdx.x] = lc;
    __syncthreads();
    for (int s = TPB / 2; s > 0; s >>= 1) {
        if (threadIdx.x < s) {
            ss[threadIdx.x] += ss[threadIdx.x + s];
            sc[threadIdx.x] += sc[threadIdx.x + s];
        }
        __syncthreads();
    }
    if (threadIdx.x == 0) {
        out[0] = (sc[0] > 0) ? (float)(ss[0] / (double)sc[0]) : 0.0f;
    }
}

extern "C" void kernel_launch(void* const* d_in, const int* in_sizes, int n_in,
                              void* d_out, int out_size, void* d_ws, size_t ws_size,
                              hipStream_t stream) {
    const float*  preds   = (const float*)d_in[0];
    const float2* targets = (const float2*)d_in[1];   // [n] of (dur, ev)
    float* out = (float*)d_out;
    int n = in_sizes[0];   // 8192

    int colGroups = n / (TPB * NB);                // 4
    int aChunks   = n / ACHUNK;                    // 128
    int nblocks   = colGroups * aChunks;           // 512

    // ws layout: psum[nblocks], pcnt[nblocks]
    float* psum = (float*)d_ws;
    int*   pcnt = (int*)(psum + nblocks);

    pair_fused<<<nblocks, TPB, 0, stream>>>(preds, targets, psum, pcnt, n);
    finalize_kernel<<<1, TPB, 0, stream>>>(psum, pcnt, out, nblocks);
}